// Round 9
// baseline (426.722 us; speedup 1.0000x reference)
//
#include <hip/hip_runtime.h>

#define CIN 8
#define FN 4
#define HSZ 256
#define NB 8

#define PV1F 16777216.0f                  /* 2^24 exactly */
#define PV2F 671088.0f                    /* floor(2^31/3200) */
#define ACT_C 1.7198652168210516e-07f     /* 2*log2(e)/2^24 */

// returns floor(tanh(floor(s)/2^24) * 2^24)  -- next layer's input, pre-scaled
__device__ __forceinline__ float act_t(float s) {
    float e = __builtin_amdgcn_exp2f(floorf(s) * ACT_C);
    float r = __builtin_amdgcn_rcpf(e + 1.0f);
    return floorf(fmaf(-33554432.0f, r, 16777216.0f));
}
// final layer: returns tanh(floor(s)/2^24)
__device__ __forceinline__ float act_out(float s) {
    float e = __builtin_amdgcn_exp2f(floorf(s) * ACT_C);
    float r = __builtin_amdgcn_rcpf(e + 1.0f);
    return fmaf(-2.0f, r, 1.0f);
}

// -------- prep: totalistic kernel (blocks 0..31) + weight transpose (32..35) --------
__global__ void k_prep(const float* __restrict__ kern,
                       const float* __restrict__ W2, const float* __restrict__ W3,
                       const float* __restrict__ W4,
                       float* __restrict__ ktot, float* __restrict__ w2t,
                       float* __restrict__ w3t, float* __restrict__ w4t) {
    int bb = blockIdx.x;
    int t = threadIdx.x;
    if (bb < 32) {
        const float* kk = kern + bb * 25;
        __shared__ float zsh[25];
        if (t < 25) {
            int i = t / 5, j = t % 5;
            float v = kk[i*5 + j] + kk[(4-i)*5 + j] + kk[i*5 + (4-j)] + kk[(4-i)*5 + (4-j)]
                    + kk[j*5 + i] + kk[j*5 + (4-i)] + kk[(4-j)*5 + i] + kk[(4-j)*5 + (4-i)];
            zsh[t] = 0.125f * v;
        }
        __syncthreads();
        if (t < 25) {
            float m = 0.0f;
            #pragma unroll
            for (int q = 0; q < 25; q++) m += zsh[q];
            m *= (1.0f / 25.0f);
            ktot[bb * 25 + t] = zsh[t] - m;
        }
    } else {
        int f = bb - 32;
        for (int e = t; e < 1024; e += 64) {
            int o = e >> 5, c = e & 31;
            w2t[f * 1024 + c * 32 + o] = W2[f * 1024 + e];   // [c][o]
            w3t[f * 1024 + c * 32 + o] = W3[f * 1024 + e];   // [c][o]
        }
        for (int e = t; e < 256; e += 64) {
            int o = e >> 5, c = e & 31;
            w4t[f * 256 + c * 8 + o] = W4[f * 256 + e];      // [c][8]
        }
    }
}

// -------- main: one wave per filter; weights staged in LDS, read as uniform b128 --------
__global__ __launch_bounds__(256, 2) void k_main(
    const float* __restrict__ x, const float* __restrict__ ktot,
    const float* __restrict__ biases, const float* __restrict__ W1,
    const float* __restrict__ w2t, const float* __restrict__ w3t,
    const float* __restrict__ w4t, const unsigned* __restrict__ urate,
    float* __restrict__ out)
{
    int tid = threadIdx.x;
    int lane = tid & 63;
    int f = __builtin_amdgcn_readfirstlane(tid >> 6);   // wave-uniform -> SGPR

    int blk = blockIdx.x;            // 8192 = b(8) * h(256) * seg(4)
    int seg = blk & 3;
    int h   = (blk >> 2) & 255;
    int b   = blk >> 10;
    int w0  = seg << 6;

    // smem aliased: conv tile zt[8][5][68] (2720 floats), then act[32][256]
    __shared__ float smem[32 * 256];                 // 32 KB
    __shared__ float red[8][FN][64];                 // 8 KB
    __shared__ float4 wl4[FN * 576];                 // 36.9 KB: per f: w2(256q) w3(256q) w4(64q)
    __shared__ float w1l[FN * 32];                   // 512 B
    __shared__ float bl[FN];
    float (*zt)[5][68] = reinterpret_cast<float(*)[5][68]>(smem);

    // ---- stage weights into LDS (w2t/w3t/w4t already transposed by k_prep) ----
    {
        const float4* w2q = (const float4*)w2t;      // [4][256] quads
        const float4* w3q = (const float4*)w3t;      // [4][256]
        const float4* w4q = (const float4*)w4t;      // [4][64]
        #pragma unroll
        for (int e = tid; e < FN * 576; e += 256) {
            int ff = e / 576, r = e - ff * 576;
            float4 v;
            if (r < 256)      v = w2q[ff * 256 + r];
            else if (r < 512) v = w3q[ff * 256 + (r - 256)];
            else              v = w4q[ff * 64 + (r - 512)];
            wl4[e] = v;
        }
        if (tid < FN * 32) w1l[tid] = W1[tid];
        if (tid < FN)      bl[tid]  = biases[tid];
    }

    // ---- stage z = floor(x*PV2) for rows h-2..h+2, cols w0-2..w0+65 (wrapped) ----
    for (int e = tid; e < CIN * 5 * 68; e += 256) {
        int c  = e / (5 * 68);
        int r  = e % (5 * 68);
        int di = r / 68;
        int dj = r % 68;
        int hh = (h + di + 254) & 255;
        int ww = (w0 + dj + 254) & 255;
        float xv = x[((b * CIN + c) << 16) + (hh << 8) + ww];
        zt[c][di][dj] = floorf(xv * PV2F);
    }
    __syncthreads();

    // ---- conv for (pixel=lane, filter=f); 2 partial accs for ILP ----
    const float* kt = ktot + f * 200;     // [c][5][5], wave-uniform
    float accA = 0.f, accB = 0.f;
    #pragma unroll
    for (int c = 0; c < CIN; c++) {
        #pragma unroll
        for (int di = 0; di < 5; di++) {
            #pragma unroll
            for (int dj = 0; dj < 5; dj++) {
                float v = zt[c][di][lane + dj] * kt[c * 25 + di * 5 + dj];
                if ((di ^ c) & 1) accA += v; else accB += v;
            }
        }
    }
    float acc = accA + accB;
    __syncthreads();                      // all waves done reading zt; smem -> act

    // ---- MLP; acts in act[c][tid] columns; weights via uniform ds_read_b128 ----
    float p  = floorf(acc + bl[f]) / PV2F;
    float t0 = floorf(p * PV1F);

    const float4* wfq = wl4 + f * 576;    // wave-uniform LDS base

    // layer 1 (c-dim == 1)
    #pragma unroll
    for (int o = 0; o < 32; o++)
        smem[o * 256 + tid] = act_t(w1l[f * 32 + o] * t0);

    // layer 2: weights wfq[0..255]
    {
        float s[32];
        #pragma unroll
        for (int o = 0; o < 32; o++) s[o] = 0.f;
        #pragma unroll
        for (int c = 0; c < 32; c++) {
            float tav = smem[c * 256 + tid];
            const float4* wq = wfq + c * 8;
            #pragma unroll
            for (int o4 = 0; o4 < 8; o4++) {
                float4 wv = wq[o4];
                s[o4*4+0] = fmaf(wv.x, tav, s[o4*4+0]);
                s[o4*4+1] = fmaf(wv.y, tav, s[o4*4+1]);
                s[o4*4+2] = fmaf(wv.z, tav, s[o4*4+2]);
                s[o4*4+3] = fmaf(wv.w, tav, s[o4*4+3]);
            }
        }
        #pragma unroll
        for (int o = 0; o < 32; o++) smem[o * 256 + tid] = act_t(s[o]);
    }

    // layer 3: weights wfq[256..511]
    {
        float s[32];
        #pragma unroll
        for (int o = 0; o < 32; o++) s[o] = 0.f;
        #pragma unroll
        for (int c = 0; c < 32; c++) {
            float tav = smem[c * 256 + tid];
            const float4* wq = wfq + 256 + c * 8;
            #pragma unroll
            for (int o4 = 0; o4 < 8; o4++) {
                float4 wv = wq[o4];
                s[o4*4+0] = fmaf(wv.x, tav, s[o4*4+0]);
                s[o4*4+1] = fmaf(wv.y, tav, s[o4*4+1]);
                s[o4*4+2] = fmaf(wv.z, tav, s[o4*4+2]);
                s[o4*4+3] = fmaf(wv.w, tav, s[o4*4+3]);
            }
        }
        #pragma unroll
        for (int o = 0; o < 32; o++) smem[o * 256 + tid] = act_t(s[o]);
    }

    // layer 4 -> 8 outputs: weights wfq[512..575], layout [c][8]
    {
        float s[8];
        #pragma unroll
        for (int o = 0; o < 8; o++) s[o] = 0.f;
        #pragma unroll
        for (int c = 0; c < 32; c++) {
            float tav = smem[c * 256 + tid];
            const float4* wq = wfq + 512 + c * 2;
            #pragma unroll
            for (int oq = 0; oq < 2; oq++) {
                float4 wv = wq[oq];
                s[oq*4+0] = fmaf(wv.x, tav, s[oq*4+0]);
                s[oq*4+1] = fmaf(wv.y, tav, s[oq*4+1]);
                s[oq*4+2] = fmaf(wv.z, tav, s[oq*4+2]);
                s[oq*4+3] = fmaf(wv.w, tav, s[oq*4+3]);
            }
        }
        #pragma unroll
        for (int o = 0; o < 8; o++) red[o][f][lane] = act_out(s[o]);
    }
    __syncthreads();

    // ---- second-smallest across f + residual + clip; 2 (o,pixel) pairs/thread ----
    unsigned ub = urate[0];
    float ur = (ub < 0x38000000u) ? (float)(int)ub : __uint_as_float(ub);

    #pragma unroll
    for (int q = 0; q < 2; q++) {
        int pidx = tid + q * 256;
        int o   = pidx >> 6;
        int pix = pidx & 63;
        float v0 = red[o][0][pix], v1 = red[o][1][pix];
        float v2 = red[o][2][pix], v3 = red[o][3][pix];
        float lo01 = fminf(v0, v1), hi01 = fmaxf(v0, v1);
        float lo23 = fminf(v2, v3), hi23 = fmaxf(v2, v3);
        float second = fminf(fmaxf(lo01, lo23), fminf(hi01, hi23));
        int oidx = ((b * CIN + o) << 16) + (h << 8) + (w0 + pix);
        float xv = x[oidx];
        out[oidx] = fminf(fmaxf(xv + second * ur, 0.0f), 1.0f);
    }
}

extern "C" void kernel_launch(void* const* d_in, const int* in_sizes, int n_in,
                              void* d_out, int out_size, void* d_ws, size_t ws_size,
                              hipStream_t stream) {
    const float* x       = (const float*)d_in[0];
    const float* kernels = (const float*)d_in[1];
    const float* biases  = (const float*)d_in[2];
    const float* W1      = (const float*)d_in[3];
    const float* W2      = (const float*)d_in[4];
    const float* W3      = (const float*)d_in[5];
    const float* W4      = (const float*)d_in[6];
    const unsigned* ur   = (const unsigned*)d_in[7];
    float* out = (float*)d_out;

    float* ktot = (float*)d_ws;                 // 800 floats
    float* w2t  = ktot + 800;                   // 4096
    float* w3t  = w2t + 4096;                   // 4096
    float* w4t  = w3t + 4096;                   // 1024   (total 9.25K floats = 37 KB)

    k_prep<<<36, 64, 0, stream>>>(kernels, W2, W3, W4, ktot, w2t, w3t, w4t);
    k_main<<<NB * HSZ * 4, 256, 0, stream>>>(x, ktot, biases, W1, w2t, w3t, w4t, ur, out);
}

// Round 10
// 231.690 us; speedup vs baseline: 1.8418x; 1.8418x over previous
//
#include <hip/hip_runtime.h>
#include <stdint.h>

#define CIN 8
#define FN 4

#define PV1F 16777216.0f                  /* 2^24 exactly */
#define PV2F 671088.0f                    /* floor(2^31/3200) */
#define ACT_C 1.7198652168210516e-07f     /* 2*log2(e)/2^24 */

typedef __attribute__((ext_vector_type(8))) short bf16x8;
typedef __attribute__((ext_vector_type(4))) float f32x4;
union FRAG { bf16x8 v; uint32_t u[4]; };

__device__ __forceinline__ float act_t(float s) {     // floor(tanh(floor(s)/2^24)*2^24)
    float e = __builtin_amdgcn_exp2f(floorf(s) * ACT_C);
    float r = __builtin_amdgcn_rcpf(e + 1.0f);
    return floorf(fmaf(-33554432.0f, r, 16777216.0f));
}
__device__ __forceinline__ float act_out(float s) {   // tanh(floor(s)/2^24)
    float e = __builtin_amdgcn_exp2f(floorf(s) * ACT_C);
    float r = __builtin_amdgcn_rcpf(e + 1.0f);
    return fmaf(-2.0f, r, 1.0f);
}
__device__ __forceinline__ uint32_t bf16_rne(float x) {
    uint32_t u = __float_as_uint(x);
    return (u + 0x7fffu + ((u >> 16) & 1u)) >> 16;
}
// split t into bf16 hi/lo, packed (hi<<16)|lo
__device__ __forceinline__ uint32_t pack_split(float t) {
    uint32_t hi = bf16_rne(t);
    float hif = __uint_as_float(hi << 16);
    uint32_t lo = bf16_rne(t - hif);
    return (hi << 16) | (lo & 0xffffu);
}

// ---------------- prep A: totalistic kernel ----------------
__global__ void k_prep(const float* __restrict__ kern, float* __restrict__ ktot) {
    int fc = blockIdx.x;                 // 0..31
    const float* kk = kern + fc * 25;
    __shared__ float zsh[25];
    int t = threadIdx.x;
    if (t < 25) {
        int i = t / 5, j = t % 5;
        float v = kk[i*5 + j] + kk[(4-i)*5 + j] + kk[i*5 + (4-j)] + kk[(4-i)*5 + (4-j)]
                + kk[j*5 + i] + kk[j*5 + (4-i)] + kk[(4-j)*5 + i] + kk[(4-j)*5 + (4-i)];
        zsh[t] = 0.125f * v;
    }
    __syncthreads();
    if (t < 25) {
        float m = 0.0f;
        #pragma unroll
        for (int q = 0; q < 25; q++) m += zsh[q];
        m *= (1.0f / 25.0f);
        ktot[fc * 25 + t] = zsh[t] - m;
    }
}

// ---------------- prep B: build MFMA A-fragments (bf16 hi/lo split) ----------------
// slot 0/1: W2 o-tiles 0,1; slot 2/3: W3; slot 4: W4 (rows 8..15 zero)
// element e = ((f*5+slot)*4+reg)*64+lane; lane holds A[m=lane&15][k=(lane>>4)*8+2r(+1)]
__global__ void k_wprep(const float* __restrict__ W2, const float* __restrict__ W3,
                        const float* __restrict__ W4,
                        uint32_t* __restrict__ whi, uint32_t* __restrict__ wlo) {
    int e = blockIdx.x * 256 + threadIdx.x;       // 4*5*4*64 = 5120
    if (e >= 5120) return;
    int lane = e & 63;
    int reg  = (e >> 6) & 3;
    int fs   = e >> 8;                            // f*5 + slot
    int slot = fs % 5, f = fs / 5;
    int m  = lane & 15;
    int k0 = (lane >> 4) * 8 + reg * 2;
    float wa = 0.f, wb = 0.f;
    if (slot < 2) {
        int o = slot * 16 + m;
        wa = W2[f*1024 + o*32 + k0]; wb = W2[f*1024 + o*32 + k0 + 1];
    } else if (slot < 4) {
        int o = (slot - 2) * 16 + m;
        wa = W3[f*1024 + o*32 + k0]; wb = W3[f*1024 + o*32 + k0 + 1];
    } else if (m < 8) {
        wa = W4[f*256 + m*32 + k0]; wb = W4[f*256 + m*32 + k0 + 1];
    }
    uint32_t ha = bf16_rne(wa), hb = bf16_rne(wb);
    uint32_t la = bf16_rne(wa - __uint_as_float(ha << 16));
    uint32_t lb = bf16_rne(wb - __uint_as_float(hb << 16));
    whi[e] = (ha & 0xffffu) | (hb << 16);        // k even in low16
    wlo[e] = (la & 0xffffu) | (lb << 16);
}

// ---------------- MFMA layer: 32 in -> 32 out over 64 pixels (one wave) ----------------
template<int S0>
__device__ __forceinline__ void mlayer(const uint32_t (&Ahi)[5][4], const uint32_t (&Alo)[5][4],
                                       uint32_t* actw, int lane) {
    uint32_t rb[4][8];
    int kb = (lane >> 4) * 8, nn = lane & 15;
    #pragma unroll
    for (int pt = 0; pt < 4; pt++)
        #pragma unroll
        for (int j = 0; j < 8; j++)
            rb[pt][j] = actw[(kb + j) * 65 + pt * 16 + nn];   // all reads before any write
    #pragma unroll
    for (int pt = 0; pt < 4; pt++) {
        FRAG bh, bl;
        #pragma unroll
        for (int r = 0; r < 4; r++) {
            bh.u[r] = (rb[pt][2*r] >> 16)     | (rb[pt][2*r+1] & 0xffff0000u);
            bl.u[r] = (rb[pt][2*r] & 0xffffu) | (rb[pt][2*r+1] << 16);
        }
        #pragma unroll
        for (int ot = 0; ot < 2; ot++) {
            FRAG ah, al;
            #pragma unroll
            for (int r = 0; r < 4; r++) { ah.u[r] = Ahi[S0+ot][r]; al.u[r] = Alo[S0+ot][r]; }
            f32x4 acc = {0.f, 0.f, 0.f, 0.f};
            acc = __builtin_amdgcn_mfma_f32_16x16x32_bf16(ah.v, bh.v, acc, 0, 0, 0);
            acc = __builtin_amdgcn_mfma_f32_16x16x32_bf16(al.v, bh.v, acc, 0, 0, 0);
            acc = __builtin_amdgcn_mfma_f32_16x16x32_bf16(ah.v, bl.v, acc, 0, 0, 0);
            acc = __builtin_amdgcn_mfma_f32_16x16x32_bf16(al.v, bl.v, acc, 0, 0, 0);
            #pragma unroll
            for (int r = 0; r < 4; r++) {
                int c = ot * 16 + (lane >> 4) * 4 + r;
                actw[c * 65 + pt * 16 + nn] = pack_split(act_t(acc[r]));
            }
        }
    }
}

// ---------------- main ----------------
__global__ __launch_bounds__(256, 3) void k_main(
    const float* __restrict__ x, const float* __restrict__ ktot,
    const float* __restrict__ biases, const float* __restrict__ W1,
    const uint32_t* __restrict__ whi, const uint32_t* __restrict__ wlo,
    const unsigned* __restrict__ urate, float* __restrict__ out)
{
    int tid = threadIdx.x;
    int lane = tid & 63;
    int f = __builtin_amdgcn_readfirstlane(tid >> 6);

    int blk = blockIdx.x;            // 8192 = b(8) * h(256) * seg(4)
    int seg = blk & 3;
    int h   = (blk >> 2) & 255;
    int b   = blk >> 10;
    int w0  = seg << 6;

    __shared__ float zt[CIN][5][68];        // 10.88 KB
    __shared__ uint32_t actb[FN][32 * 65];  // 33.28 KB, wave-private rows
    __shared__ float red[8][FN][64];        // 8 KB
    __shared__ float w1l[FN * 32];
    __shared__ float bl[FN];
    uint32_t* actw = &actb[f][0];

    if (tid < FN * 32) w1l[tid] = W1[tid];
    if (tid < FN)      bl[tid]  = biases[tid];

    // ---- stage z = floor(x*PV2), rows h-2..h+2, cols w0-2..w0+65 (wrapped) ----
    for (int e = tid; e < CIN * 5 * 68; e += 256) {
        int c  = e / (5 * 68);
        int r  = e % (5 * 68);
        int di = r / 68;
        int dj = r % 68;
        int hh = (h + di + 254) & 255;
        int ww = (w0 + dj + 254) & 255;
        float xv = x[((b * CIN + c) << 16) + (hh << 8) + ww];
        zt[c][di][dj] = floorf(xv * PV2F);
    }
    __syncthreads();

    // ---- conv (pixel=lane, filter=f) ----
    const float* kt = ktot + f * 200;
    float accA = 0.f, accB = 0.f;
    #pragma unroll
    for (int c = 0; c < CIN; c++) {
        #pragma unroll
        for (int di = 0; di < 5; di++) {
            #pragma unroll
            for (int dj = 0; dj < 5; dj++) {
                float v = zt[c][di][lane + dj] * kt[c * 25 + di * 5 + dj];
                if ((di ^ c) & 1) accA += v; else accB += v;
            }
        }
    }
    float p  = floorf(accA + accB + bl[f]) / PV2F;
    float t0 = floorf(p * PV1F);

    // ---- load A-fragments (whi/wlo) ----
    uint32_t Ahi[5][4], Alo[5][4];
    #pragma unroll
    for (int s5 = 0; s5 < 5; s5++)
        #pragma unroll
        for (int r = 0; r < 4; r++) {
            int idx = ((f * 5 + s5) * 4 + r) * 64 + lane;
            Ahi[s5][r] = whi[idx];
            Alo[s5][r] = wlo[idx];
        }

    // ---- layer 1 (rank-1): act -> packed LDS [c][pix] ----
    #pragma unroll
    for (int o = 0; o < 32; o++)
        actw[o * 65 + lane] = pack_split(act_t(w1l[f * 32 + o] * t0));

    // ---- layers 2,3 via MFMA ----
    mlayer<0>(Ahi, Alo, actw, lane);
    mlayer<2>(Ahi, Alo, actw, lane);

    // ---- layer 4 via MFMA (8 outputs) ----
    {
        uint32_t rb[4][8];
        int kb = (lane >> 4) * 8, nn = lane & 15;
        #pragma unroll
        for (int pt = 0; pt < 4; pt++)
            #pragma unroll
            for (int j = 0; j < 8; j++)
                rb[pt][j] = actw[(kb + j) * 65 + pt * 16 + nn];
        #pragma unroll
        for (int pt = 0; pt < 4; pt++) {
            FRAG bh, blf, ah, al;
            #pragma unroll
            for (int r = 0; r < 4; r++) {
                bh.u[r]  = (rb[pt][2*r] >> 16)     | (rb[pt][2*r+1] & 0xffff0000u);
                blf.u[r] = (rb[pt][2*r] & 0xffffu) | (rb[pt][2*r+1] << 16);
                ah.u[r] = Ahi[4][r]; al.u[r] = Alo[4][r];
            }
            f32x4 acc = {0.f, 0.f, 0.f, 0.f};
            acc = __builtin_amdgcn_mfma_f32_16x16x32_bf16(ah.v, bh.v, acc, 0, 0, 0);
            acc = __builtin_amdgcn_mfma_f32_16x16x32_bf16(al.v, bh.v, acc, 0, 0, 0);
            acc = __builtin_amdgcn_mfma_f32_16x16x32_bf16(ah.v, blf.v, acc, 0, 0, 0);
            acc = __builtin_amdgcn_mfma_f32_16x16x32_bf16(al.v, blf.v, acc, 0, 0, 0);
            if (lane < 32) {
                #pragma unroll
                for (int r = 0; r < 4; r++) {
                    int o = (lane >> 4) * 4 + r;      // 0..7
                    red[o][f][pt * 16 + nn] = act_out(acc[r]);
                }
            }
        }
    }
    __syncthreads();

    // ---- second-smallest across f + residual + clip ----
    unsigned ub = urate[0];
    float ur = (ub < 0x38000000u) ? (float)(int)ub : __uint_as_float(ub);

    #pragma unroll
    for (int q = 0; q < 2; q++) {
        int pidx = tid + q * 256;
        int o   = pidx >> 6;
        int pix = pidx & 63;
        float v0 = red[o][0][pix], v1 = red[o][1][pix];
        float v2 = red[o][2][pix], v3 = red[o][3][pix];
        float lo01 = fminf(v0, v1), hi01 = fmaxf(v0, v1);
        float lo23 = fminf(v2, v3), hi23 = fmaxf(v2, v3);
        float second = fminf(fmaxf(lo01, lo23), fminf(hi01, hi23));
        int oidx = ((b * CIN + o) << 16) + (h << 8) + (w0 + pix);
        float xv = x[oidx];
        out[oidx] = fminf(fmaxf(xv + second * ur, 0.0f), 1.0f);
    }
}

extern "C" void kernel_launch(void* const* d_in, const int* in_sizes, int n_in,
                              void* d_out, int out_size, void* d_ws, size_t ws_size,
                              hipStream_t stream) {
    const float* x       = (const float*)d_in[0];
    const float* kernels = (const float*)d_in[1];
    const float* biases  = (const float*)d_in[2];
    const float* W1      = (const float*)d_in[3];
    const float* W2      = (const float*)d_in[4];
    const float* W3      = (const float*)d_in[5];
    const float* W4      = (const float*)d_in[6];
    const unsigned* ur   = (const unsigned*)d_in[7];
    float* out = (float*)d_out;

    float*    ktot = (float*)d_ws;                  // 800 floats
    uint32_t* whi  = (uint32_t*)((float*)d_ws + 800);   // 5120 u32
    uint32_t* wlo  = whi + 5120;                        // 5120 u32

    k_prep<<<32, 64, 0, stream>>>(kernels, ktot);
    k_wprep<<<20, 256, 0, stream>>>(W2, W3, W4, whi, wlo);
    k_main<<<8 * 256 * 4, 256, 0, stream>>>(x, ktot, biases, W1, whi, wlo, ur, out);
}

// Round 12
// 213.807 us; speedup vs baseline: 1.9958x; 1.0836x over previous
//
#include <hip/hip_runtime.h>
#include <stdint.h>

#define CIN 8
#define FN 4

#define PV1F 16777216.0f                  /* 2^24 exactly */
#define PV2F 671088.0f                    /* floor(2^31/3200) */
#define ACT_C 1.7198652168210516e-07f     /* 2*log2(e)/2^24 */

typedef __attribute__((ext_vector_type(8))) short bf16x8;
typedef __attribute__((ext_vector_type(4))) float f32x4;
union FRAG { bf16x8 v; uint32_t u[4]; };

// floor() deliberately dropped: |err|<=1 on 2^24 scale = 2^-24 in tanh arg,
// far below the 2^-16 bf16-split representation error already in the pipeline.
__device__ __forceinline__ float act_t(float s) {     // ~ tanh(s/2^24)*2^24
    float e = __builtin_amdgcn_exp2f(s * ACT_C);
    float r = __builtin_amdgcn_rcpf(e + 1.0f);
    return fmaf(-33554432.0f, r, 16777216.0f);
}
__device__ __forceinline__ float act_out(float s) {   // ~ tanh(s/2^24)
    float e = __builtin_amdgcn_exp2f(s * ACT_C);
    float r = __builtin_amdgcn_rcpf(e + 1.0f);
    return fmaf(-2.0f, r, 1.0f);
}
__device__ __forceinline__ uint32_t bf16_rne(float x) {
    uint32_t u = __float_as_uint(x);
    return (u + 0x7fffu + ((u >> 16) & 1u)) >> 16;
}
// split t into bf16 hi (truncated) / lo (RNE via HW cvt), packed (hi16<<16)|lo16
__device__ __forceinline__ uint32_t pack_split(float t) {
    uint32_t u = __float_as_uint(t);
    uint32_t hbits = u & 0xffff0000u;                 // trunc-to-bf16 of t
    float r = t - __uint_as_float(hbits);             // exact residual
    uint32_t lo;
    asm("v_cvt_pk_bf16_f32 %0, %1, %2" : "=v"(lo) : "v"(r), "v"(r));
    return hbits | (lo & 0xffffu);                    // robust to pack order
}

// ---------------- prep A: totalistic kernel ----------------
__global__ void k_prep(const float* __restrict__ kern, float* __restrict__ ktot) {
    int fc = blockIdx.x;                 // 0..31
    const float* kk = kern + fc * 25;
    __shared__ float zsh[25];
    int t = threadIdx.x;
    if (t < 25) {
        int i = t / 5, j = t % 5;
        float v = kk[i*5 + j] + kk[(4-i)*5 + j] + kk[i*5 + (4-j)] + kk[(4-i)*5 + (4-j)]
                + kk[j*5 + i] + kk[j*5 + (4-i)] + kk[(4-j)*5 + i] + kk[(4-j)*5 + (4-i)];
        zsh[t] = 0.125f * v;
    }
    __syncthreads();
    if (t < 25) {
        float m = 0.0f;
        #pragma unroll
        for (int q = 0; q < 25; q++) m += zsh[q];
        m *= (1.0f / 25.0f);
        ktot[fc * 25 + t] = zsh[t] - m;
    }
}

// ---------------- prep B: build MFMA A-fragments (bf16 hi/lo split) ----------------
__global__ void k_wprep(const float* __restrict__ W2, const float* __restrict__ W3,
                        const float* __restrict__ W4,
                        uint32_t* __restrict__ whi, uint32_t* __restrict__ wlo) {
    int e = blockIdx.x * 256 + threadIdx.x;       // 4*5*4*64 = 5120
    if (e >= 5120) return;
    int lane = e & 63;
    int reg  = (e >> 6) & 3;
    int fs   = e >> 8;                            // f*5 + slot
    int slot = fs % 5, f = fs / 5;
    int m  = lane & 15;
    int k0 = (lane >> 4) * 8 + reg * 2;
    float wa = 0.f, wb = 0.f;
    if (slot < 2) {
        int o = slot * 16 + m;
        wa = W2[f*1024 + o*32 + k0]; wb = W2[f*1024 + o*32 + k0 + 1];
    } else if (slot < 4) {
        int o = (slot - 2) * 16 + m;
        wa = W3[f*1024 + o*32 + k0]; wb = W3[f*1024 + o*32 + k0 + 1];
    } else if (m < 8) {
        wa = W4[f*256 + m*32 + k0]; wb = W4[f*256 + m*32 + k0 + 1];
    }
    uint32_t ha = bf16_rne(wa), hb = bf16_rne(wb);
    uint32_t la = bf16_rne(wa - __uint_as_float(ha << 16));
    uint32_t lb = bf16_rne(wb - __uint_as_float(hb << 16));
    whi[e] = (ha & 0xffffu) | (hb << 16);        // k even in low16
    wlo[e] = (la & 0xffffu) | (lb << 16);
}

// ---------------- MFMA layer: 32 in -> 32 out over 64 pixels (one wave) ----------------
// 3-term split: ah*bh + al*bh + ah*bl (al*bl ~ 2^-18 rel, dropped)
template<int S0>
__device__ __forceinline__ void mlayer(const uint32_t (&Ahi)[5][4], const uint32_t (&Alo)[5][4],
                                       uint32_t* actw, int lane) {
    uint32_t rb[4][8];
    int kb = (lane >> 4) * 8, nn = lane & 15;
    #pragma unroll
    for (int pt = 0; pt < 4; pt++)
        #pragma unroll
        for (int j = 0; j < 8; j++)
            rb[pt][j] = actw[(kb + j) * 65 + pt * 16 + nn];   // all reads before any write
    #pragma unroll
    for (int pt = 0; pt < 4; pt++) {
        FRAG bh, bl;
        #pragma unroll
        for (int r = 0; r < 4; r++) {
            bh.u[r] = (rb[pt][2*r] >> 16)     | (rb[pt][2*r+1] & 0xffff0000u);
            bl.u[r] = (rb[pt][2*r] & 0xffffu) | (rb[pt][2*r+1] << 16);
        }
        #pragma unroll
        for (int ot = 0; ot < 2; ot++) {
            FRAG ah, al;
            #pragma unroll
            for (int r = 0; r < 4; r++) { ah.u[r] = Ahi[S0+ot][r]; al.u[r] = Alo[S0+ot][r]; }
            f32x4 acc = {0.f, 0.f, 0.f, 0.f};
            acc = __builtin_amdgcn_mfma_f32_16x16x32_bf16(ah.v, bh.v, acc, 0, 0, 0);
            acc = __builtin_amdgcn_mfma_f32_16x16x32_bf16(al.v, bh.v, acc, 0, 0, 0);
            acc = __builtin_amdgcn_mfma_f32_16x16x32_bf16(ah.v, bl.v, acc, 0, 0, 0);
            #pragma unroll
            for (int r = 0; r < 4; r++) {
                int c = ot * 16 + (lane >> 4) * 4 + r;
                actw[c * 65 + pt * 16 + nn] = pack_split(act_t(acc[r]));
            }
        }
    }
}

// ---------------- main ----------------
__global__ __launch_bounds__(256, 3) void k_main(
    const float* __restrict__ x, const float* __restrict__ ktot,
    const float* __restrict__ biases, const float* __restrict__ W1,
    const uint32_t* __restrict__ whi, const uint32_t* __restrict__ wlo,
    const unsigned* __restrict__ urate, float* __restrict__ out)
{
    int tid = threadIdx.x;
    int lane = tid & 63;
    int f = __builtin_amdgcn_readfirstlane(tid >> 6);

    int blk = blockIdx.x;            // 8192 = b(8) * h(256) * seg(4)
    int seg = blk & 3;
    int h   = (blk >> 2) & 255;
    int b   = blk >> 10;
    int w0  = seg << 6;

    __shared__ float zt[CIN][5][68];        // 10.88 KB
    __shared__ uint32_t actb[FN][32 * 65];  // 33.28 KB, wave-private rows
    __shared__ float red[8][FN][64];        // 8 KB
    __shared__ float w1l[FN * 32];
    __shared__ float bl[FN];
    uint32_t* actw = &actb[f][0];

    if (tid < FN * 32) w1l[tid] = W1[tid];
    if (tid < FN)      bl[tid]  = biases[tid];

    // ---- stage z = floor(x*PV2), rows h-2..h+2, cols w0-2..w0+65 (wrapped) ----
    for (int e = tid; e < CIN * 5 * 68; e += 256) {
        int c  = e / (5 * 68);
        int r  = e % (5 * 68);
        int di = r / 68;
        int dj = r % 68;
        int hh = (h + di + 254) & 255;
        int ww = (w0 + dj + 254) & 255;
        float xv = x[((b * CIN + c) << 16) + (hh << 8) + ww];
        zt[c][di][dj] = floorf(xv * PV2F);
    }
    __syncthreads();

    // ---- conv (pixel=lane, filter=f) ----
    const float* kt = ktot + f * 200;
    float accA = 0.f, accB = 0.f;
    #pragma unroll
    for (int c = 0; c < CIN; c++) {
        #pragma unroll
        for (int di = 0; di < 5; di++) {
            #pragma unroll
            for (int dj = 0; dj < 5; dj++) {
                float v = zt[c][di][lane + dj] * kt[c * 25 + di * 5 + dj];
                if ((di ^ c) & 1) accA += v; else accB += v;
            }
        }
    }
    float p  = floorf(accA + accB + bl[f]) / PV2F;
    float t0 = floorf(p * PV1F);

    // ---- load A-fragments (whi/wlo) ----
    uint32_t Ahi[5][4], Alo[5][4];
    #pragma unroll
    for (int s5 = 0; s5 < 5; s5++)
        #pragma unroll
        for (int r = 0; r < 4; r++) {
            int idx = ((f * 5 + s5) * 4 + r) * 64 + lane;
            Ahi[s5][r] = whi[idx];
            Alo[s5][r] = wlo[idx];
        }

    // ---- layer 1 (rank-1): act -> packed LDS [c][pix] ----
    #pragma unroll
    for (int o = 0; o < 32; o++)
        actw[o * 65 + lane] = pack_split(act_t(w1l[f * 32 + o] * t0));

    // ---- layers 2,3 via MFMA ----
    mlayer<0>(Ahi, Alo, actw, lane);
    mlayer<2>(Ahi, Alo, actw, lane);

    // ---- layer 4 via MFMA (8 outputs) ----
    {
        uint32_t rb[4][8];
        int kb = (lane >> 4) * 8, nn = lane & 15;
        #pragma unroll
        for (int pt = 0; pt < 4; pt++)
            #pragma unroll
            for (int j = 0; j < 8; j++)
                rb[pt][j] = actw[(kb + j) * 65 + pt * 16 + nn];
        #pragma unroll
        for (int pt = 0; pt < 4; pt++) {
            FRAG bh, blf, ah, al;
            #pragma unroll
            for (int r = 0; r < 4; r++) {
                bh.u[r]  = (rb[pt][2*r] >> 16)     | (rb[pt][2*r+1] & 0xffff0000u);
                blf.u[r] = (rb[pt][2*r] & 0xffffu) | (rb[pt][2*r+1] << 16);
                ah.u[r] = Ahi[4][r]; al.u[r] = Alo[4][r];
            }
            f32x4 acc = {0.f, 0.f, 0.f, 0.f};
            acc = __builtin_amdgcn_mfma_f32_16x16x32_bf16(ah.v, bh.v, acc, 0, 0, 0);
            acc = __builtin_amdgcn_mfma_f32_16x16x32_bf16(al.v, bh.v, acc, 0, 0, 0);
            acc = __builtin_amdgcn_mfma_f32_16x16x32_bf16(ah.v, blf.v, acc, 0, 0, 0);
            if (lane < 32) {
                #pragma unroll
                for (int r = 0; r < 4; r++) {
                    int o = (lane >> 4) * 4 + r;      // 0..7
                    red[o][f][pt * 16 + nn] = act_out(acc[r]);
                }
            }
        }
    }
    __syncthreads();

    // ---- second-smallest across f + residual + clip ----
    unsigned ub = urate[0];
    float ur = (ub < 0x38000000u) ? (float)(int)ub : __uint_as_float(ub);

    #pragma unroll
    for (int q = 0; q < 2; q++) {
        int pidx = tid + q * 256;
        int o   = pidx >> 6;
        int pix = pidx & 63;
        float v0 = red[o][0][pix], v1 = red[o][1][pix];
        float v2 = red[o][2][pix], v3 = red[o][3][pix];
        float lo01 = fminf(v0, v1), hi01 = fmaxf(v0, v1);
        float lo23 = fminf(v2, v3), hi23 = fmaxf(v2, v3);
        float second = fminf(fmaxf(lo01, lo23), fminf(hi01, hi23));
        int oidx = ((b * CIN + o) << 16) + (h << 8) + (w0 + pix);
        float xv = x[oidx];
        out[oidx] = fminf(fmaxf(xv + second * ur, 0.0f), 1.0f);
    }
}

extern "C" void kernel_launch(void* const* d_in, const int* in_sizes, int n_in,
                              void* d_out, int out_size, void* d_ws, size_t ws_size,
                              hipStream_t stream) {
    const float* x       = (const float*)d_in[0];
    const float* kernels = (const float*)d_in[1];
    const float* biases  = (const float*)d_in[2];
    const float* W1      = (const float*)d_in[3];
    const float* W2      = (const float*)d_in[4];
    const float* W3      = (const float*)d_in[5];
    const float* W4      = (const float*)d_in[6];
    const unsigned* ur   = (const unsigned*)d_in[7];
    float* out = (float*)d_out;

    float*    ktot = (float*)d_ws;                  // 800 floats
    uint32_t* whi  = (uint32_t*)((float*)d_ws + 800);   // 5120 u32
    uint32_t* wlo  = whi + 5120;                        // 5120 u32

    k_prep<<<32, 64, 0, stream>>>(kernels, ktot);
    k_wprep<<<20, 256, 0, stream>>>(W2, W3, W4, whi, wlo);
    k_main<<<8 * 256 * 4, 256, 0, stream>>>(x, ktot, biases, W1, whi, wlo, ur, out);
}

// Round 13
// 168.845 us; speedup vs baseline: 2.5273x; 1.2663x over previous
//
#include <hip/hip_runtime.h>
#include <stdint.h>

#define CIN 8
#define FN 4
#define APAD 66

#define PV1F 16777216.0f                  /* 2^24 exactly */
#define PV2F 671088.0f                    /* floor(2^31/3200) */
#define ACT_C 1.7198652168210516e-07f     /* 2*log2(e)/2^24 */

typedef __attribute__((ext_vector_type(8))) short bf16x8;
typedef __attribute__((ext_vector_type(4))) float f32x4;
union FRAG { bf16x8 v; uint32_t u[4]; };

// floor() dropped: |err|<=1 on the 2^24 scale = 2^-24 in the tanh arg,
// far below the bf16 activation quantization (2^-9) now in the pipeline.
__device__ __forceinline__ float act_t(float s) {     // ~ tanh(s/2^24)*2^24
    float e = __builtin_amdgcn_exp2f(s * ACT_C);
    float r = __builtin_amdgcn_rcpf(e + 1.0f);
    return fmaf(-33554432.0f, r, 16777216.0f);
}
__device__ __forceinline__ float act_out(float s) {   // ~ tanh(s/2^24)
    float e = __builtin_amdgcn_exp2f(s * ACT_C);
    float r = __builtin_amdgcn_rcpf(e + 1.0f);
    return fmaf(-2.0f, r, 1.0f);
}
__device__ __forceinline__ uint32_t bf16_rne(float x) {
    uint32_t u = __float_as_uint(x);
    return (u + 0x7fffu + ((u >> 16) & 1u)) >> 16;
}
// pack two f32 -> (bf16(t1)<<16)|bf16(t0), RNE, one HW op (src0 -> low16)
__device__ __forceinline__ uint32_t cvt_pk(float t0, float t1) {
    uint32_t r;
    asm("v_cvt_pk_bf16_f32 %0, %1, %2" : "=v"(r) : "v"(t0), "v"(t1));
    return r;
}

// ---------------- prep A: totalistic kernel ----------------
__global__ void k_prep(const float* __restrict__ kern, float* __restrict__ ktot) {
    int fc = blockIdx.x;                 // 0..31
    const float* kk = kern + fc * 25;
    __shared__ float zsh[25];
    int t = threadIdx.x;
    if (t < 25) {
        int i = t / 5, j = t % 5;
        float v = kk[i*5 + j] + kk[(4-i)*5 + j] + kk[i*5 + (4-j)] + kk[(4-i)*5 + (4-j)]
                + kk[j*5 + i] + kk[j*5 + (4-i)] + kk[(4-j)*5 + i] + kk[(4-j)*5 + (4-i)];
        zsh[t] = 0.125f * v;
    }
    __syncthreads();
    if (t < 25) {
        float m = 0.0f;
        #pragma unroll
        for (int q = 0; q < 25; q++) m += zsh[q];
        m *= (1.0f / 25.0f);
        ktot[fc * 25 + t] = zsh[t] - m;
    }
}

// ---------------- prep B: MFMA A-fragments, weights as bf16 hi/lo split ----------------
// slot 0/1: W2 o-tiles; 2/3: W3; 4: W4 (rows 8..15 zero)
// A[m=lane&15][k=(lane>>4)*8 + reg*2 (+1)]; k-even in low16
__global__ void k_wprep(const float* __restrict__ W2, const float* __restrict__ W3,
                        const float* __restrict__ W4,
                        uint32_t* __restrict__ whi, uint32_t* __restrict__ wlo) {
    int e = blockIdx.x * 256 + threadIdx.x;       // 4*5*4*64 = 5120
    if (e >= 5120) return;
    int lane = e & 63;
    int reg  = (e >> 6) & 3;
    int fs   = e >> 8;
    int slot = fs % 5, f = fs / 5;
    int m  = lane & 15;
    int k0 = (lane >> 4) * 8 + reg * 2;
    float wa = 0.f, wb = 0.f;
    if (slot < 2) {
        int o = slot * 16 + m;
        wa = W2[f*1024 + o*32 + k0]; wb = W2[f*1024 + o*32 + k0 + 1];
    } else if (slot < 4) {
        int o = (slot - 2) * 16 + m;
        wa = W3[f*1024 + o*32 + k0]; wb = W3[f*1024 + o*32 + k0 + 1];
    } else if (m < 8) {
        wa = W4[f*256 + m*32 + k0]; wb = W4[f*256 + m*32 + k0 + 1];
    }
    uint32_t ha = bf16_rne(wa), hb = bf16_rne(wb);
    uint32_t la = bf16_rne(wa - __uint_as_float(ha << 16));
    uint32_t lb = bf16_rne(wb - __uint_as_float(hb << 16));
    whi[e] = (ha & 0xffffu) | (hb << 16);
    wlo[e] = (la & 0xffffu) | (lb << 16);
}

// ---------------- MFMA layer: acts as k-pair u32 [16][APAD]; 2-term weight split ----------------
template<int S0>
__device__ __forceinline__ void mlayer(const uint32_t (&Ahi)[5][4], const uint32_t (&Alo)[5][4],
                                       uint32_t* actw, int lane) {
    int g = lane >> 4, nn = lane & 15;
    uint32_t rb[4][4];
    #pragma unroll
    for (int pt = 0; pt < 4; pt++)
        #pragma unroll
        for (int r = 0; r < 4; r++)
            rb[pt][r] = actw[(g * 4 + r) * APAD + pt * 16 + nn];  // all reads before writes
    #pragma unroll
    for (int pt = 0; pt < 4; pt++) {
        FRAG bb;
        #pragma unroll
        for (int r = 0; r < 4; r++) bb.u[r] = rb[pt][r];
        #pragma unroll
        for (int ot = 0; ot < 2; ot++) {
            FRAG ah, al;
            #pragma unroll
            for (int r = 0; r < 4; r++) { ah.u[r] = Ahi[S0+ot][r]; al.u[r] = Alo[S0+ot][r]; }
            f32x4 acc = {0.f, 0.f, 0.f, 0.f};
            acc = __builtin_amdgcn_mfma_f32_16x16x32_bf16(ah.v, bb.v, acc, 0, 0, 0);
            acc = __builtin_amdgcn_mfma_f32_16x16x32_bf16(al.v, bb.v, acc, 0, 0, 0);
            // outputs: c = ot*16 + g*4 + r at pixel pt*16+nn; pack pairs
            uint32_t p01 = cvt_pk(act_t(acc[0]), act_t(acc[1]));
            uint32_t p23 = cvt_pk(act_t(acc[2]), act_t(acc[3]));
            int cp = ot * 8 + g * 2;
            actw[cp * APAD + pt * 16 + nn]       = p01;
            actw[(cp + 1) * APAD + pt * 16 + nn] = p23;
        }
    }
}

// ---------------- main ----------------
__global__ __launch_bounds__(256, 5) void k_main(
    const float* __restrict__ x, const float* __restrict__ ktot,
    const float* __restrict__ biases, const float* __restrict__ W1,
    const uint32_t* __restrict__ whi, const uint32_t* __restrict__ wlo,
    const unsigned* __restrict__ urate, float* __restrict__ out)
{
    int tid = threadIdx.x;
    int lane = tid & 63;
    int f = __builtin_amdgcn_readfirstlane(tid >> 6);

    int blk = blockIdx.x;            // 8192 = b(8) * h(256) * seg(4)
    int seg = blk & 3;
    int h   = (blk >> 2) & 255;
    int b   = blk >> 10;
    int w0  = seg << 6;

    __shared__ float zt_red[CIN * 5 * 68];     // 10.88 KB: zt, then aliased as red[8][4][64]
    __shared__ uint32_t actb[FN][16 * APAD];   // 16.9 KB, wave-private
    __shared__ float w1l[FN * 32];
    __shared__ float bl[FN];
    float (*zt)[5][68] = reinterpret_cast<float(*)[5][68]>(zt_red);
    float* red = zt_red;                       // red[(o*FN+f)*64 + pix], 8 KB < 10.88 KB
    uint32_t* actw = &actb[f][0];

    if (tid < FN * 32) w1l[tid] = W1[tid];
    if (tid < FN)      bl[tid]  = biases[tid];

    // ---- stage z = floor(x*PV2), rows h-2..h+2, cols w0-2..w0+65 (wrapped) ----
    for (int e = tid; e < CIN * 5 * 68; e += 256) {
        int c  = e / (5 * 68);
        int r  = e % (5 * 68);
        int di = r / 68;
        int dj = r % 68;
        int hh = (h + di + 254) & 255;
        int ww = (w0 + dj + 254) & 255;
        float xv = x[((b * CIN + c) << 16) + (hh << 8) + ww];
        zt[c][di][dj] = floorf(xv * PV2F);
    }
    __syncthreads();

    // ---- conv (pixel=lane, filter=f), fp32 exact ----
    const float* kt = ktot + f * 200;
    float accA = 0.f, accB = 0.f;
    #pragma unroll
    for (int c = 0; c < CIN; c++) {
        #pragma unroll
        for (int di = 0; di < 5; di++) {
            #pragma unroll
            for (int dj = 0; dj < 5; dj++) {
                float v = zt[c][di][lane + dj] * kt[c * 25 + di * 5 + dj];
                if ((di ^ c) & 1) accA += v; else accB += v;
            }
        }
    }
    float p  = floorf(accA + accB + bl[f]) / PV2F;
    float t0 = floorf(p * PV1F);
    __syncthreads();                 // zt dead; safe to alias as red below

    // ---- load A-fragments ----
    uint32_t Ahi[5][4], Alo[5][4];
    #pragma unroll
    for (int s5 = 0; s5 < 5; s5++)
        #pragma unroll
        for (int r = 0; r < 4; r++) {
            int idx = ((f * 5 + s5) * 4 + r) * 64 + lane;
            Ahi[s5][r] = whi[idx];
            Alo[s5][r] = wlo[idx];
        }

    // ---- layer 1 (rank-1): 32 acts for this thread's pixel, packed as k-pairs ----
    #pragma unroll
    for (int op = 0; op < 16; op++) {
        float a0 = act_t(w1l[f * 32 + 2*op]     * t0);
        float a1 = act_t(w1l[f * 32 + 2*op + 1] * t0);
        actw[op * APAD + lane] = cvt_pk(a0, a1);
    }

    // ---- layers 2,3 via MFMA ----
    mlayer<0>(Ahi, Alo, actw, lane);
    mlayer<2>(Ahi, Alo, actw, lane);

    // ---- layer 4 via MFMA (8 outputs) ----
    {
        int g = lane >> 4, nn = lane & 15;
        uint32_t rb[4][4];
        #pragma unroll
        for (int pt = 0; pt < 4; pt++)
            #pragma unroll
            for (int r = 0; r < 4; r++)
                rb[pt][r] = actw[(g * 4 + r) * APAD + pt * 16 + nn];
        #pragma unroll
        for (int pt = 0; pt < 4; pt++) {
            FRAG bb, ah, al;
            #pragma unroll
            for (int r = 0; r < 4; r++) {
                bb.u[r] = rb[pt][r];
                ah.u[r] = Ahi[4][r]; al.u[r] = Alo[4][r];
            }
            f32x4 acc = {0.f, 0.f, 0.f, 0.f};
            acc = __builtin_amdgcn_mfma_f32_16x16x32_bf16(ah.v, bb.v, acc, 0, 0, 0);
            acc = __builtin_amdgcn_mfma_f32_16x16x32_bf16(al.v, bb.v, acc, 0, 0, 0);
            if (lane < 32) {
                #pragma unroll
                for (int r = 0; r < 4; r++) {
                    int o = g * 4 + r;                // 0..7
                    red[(o * FN + f) * 64 + pt * 16 + nn] = act_out(acc[r]);
                }
            }
        }
    }
    __syncthreads();

    // ---- second-smallest across f + residual + clip ----
    unsigned ub = urate[0];
    float ur = (ub < 0x38000000u) ? (float)(int)ub : __uint_as_float(ub);

    #pragma unroll
    for (int q = 0; q < 2; q++) {
        int pidx = tid + q * 256;
        int o   = pidx >> 6;
        int pix = pidx & 63;
        float v0 = red[(o * FN + 0) * 64 + pix], v1 = red[(o * FN + 1) * 64 + pix];
        float v2 = red[(o * FN + 2) * 64 + pix], v3 = red[(o * FN + 3) * 64 + pix];
        float lo01 = fminf(v0, v1), hi01 = fmaxf(v0, v1);
        float lo23 = fminf(v2, v3), hi23 = fmaxf(v2, v3);
        float second = fminf(fmaxf(lo01, lo23), fminf(hi01, hi23));
        int oidx = ((b * CIN + o) << 16) + (h << 8) + (w0 + pix);
        float xv = x[oidx];
        out[oidx] = fminf(fmaxf(xv + second * ur, 0.0f), 1.0f);
    }
}

extern "C" void kernel_launch(void* const* d_in, const int* in_sizes, int n_in,
                              void* d_out, int out_size, void* d_ws, size_t ws_size,
                              hipStream_t stream) {
    const float* x       = (const float*)d_in[0];
    const float* kernels = (const float*)d_in[1];
    const float* biases  = (const float*)d_in[2];
    const float* W1      = (const float*)d_in[3];
    const float* W2      = (const float*)d_in[4];
    const float* W3      = (const float*)d_in[5];
    const float* W4      = (const float*)d_in[6];
    const unsigned* ur   = (const unsigned*)d_in[7];
    float* out = (float*)d_out;

    float*    ktot = (float*)d_ws;                      // 800 floats
    uint32_t* whi  = (uint32_t*)((float*)d_ws + 800);   // 5120 u32
    uint32_t* wlo  = whi + 5120;                        // 5120 u32

    k_prep<<<32, 64, 0, stream>>>(kernels, ktot);
    k_wprep<<<20, 256, 0, stream>>>(W2, W3, W4, whi, wlo);
    k_main<<<8 * 256 * 4, 256, 0, stream>>>(x, ktot, biases, W1, whi, wlo, ur, out);
}

// Round 14
// 163.109 us; speedup vs baseline: 2.6162x; 1.0352x over previous
//
#include <hip/hip_runtime.h>
#include <stdint.h>

#define CIN 8
#define FN 4
#define APAD 66

#define PV1F 16777216.0f                  /* 2^24 exactly */
#define PV2F 671088.0f                    /* floor(2^31/3200) */
#define ACT_C 1.7198652168210516e-07f     /* 2*log2(e)/2^24 -- folded into weights */

typedef __attribute__((ext_vector_type(8))) short bf16x8;
typedef __attribute__((ext_vector_type(4))) float f32x4;
union FRAG { bf16x8 v; uint32_t u[4]; };

// weights pre-scaled by ACT_C, so s arrives ready for exp2.
__device__ __forceinline__ float act_t(float s) {     // ~ tanh(sC'/2) * 2^24
    float e = __builtin_amdgcn_exp2f(s);
    float r = __builtin_amdgcn_rcpf(e + 1.0f);
    return fmaf(-33554432.0f, r, 16777216.0f);
}
__device__ __forceinline__ float act_out(float s) {   // ~ tanh
    float e = __builtin_amdgcn_exp2f(s);
    float r = __builtin_amdgcn_rcpf(e + 1.0f);
    return fmaf(-2.0f, r, 1.0f);
}
__device__ __forceinline__ uint32_t bf16_rne(float x) {
    uint32_t u = __float_as_uint(x);
    return (u + 0x7fffu + ((u >> 16) & 1u)) >> 16;
}
// pack two f32 -> (bf16(t1)<<16)|bf16(t0), RNE, one HW op (src0 -> low16)
__device__ __forceinline__ uint32_t cvt_pk(float t0, float t1) {
    uint32_t r;
    asm("v_cvt_pk_bf16_f32 %0, %1, %2" : "=v"(r) : "v"(t0), "v"(t1));
    return r;
}

// ---------------- prep A: totalistic kernel ----------------
__global__ void k_prep(const float* __restrict__ kern, float* __restrict__ ktot) {
    int fc = blockIdx.x;                 // 0..31
    const float* kk = kern + fc * 25;
    __shared__ float zsh[25];
    int t = threadIdx.x;
    if (t < 25) {
        int i = t / 5, j = t % 5;
        float v = kk[i*5 + j] + kk[(4-i)*5 + j] + kk[i*5 + (4-j)] + kk[(4-i)*5 + (4-j)]
                + kk[j*5 + i] + kk[j*5 + (4-i)] + kk[(4-j)*5 + i] + kk[(4-j)*5 + (4-i)];
        zsh[t] = 0.125f * v;
    }
    __syncthreads();
    if (t < 25) {
        float m = 0.0f;
        #pragma unroll
        for (int q = 0; q < 25; q++) m += zsh[q];
        m *= (1.0f / 25.0f);
        ktot[fc * 25 + t] = zsh[t] - m;
    }
}

// ---------------- prep B: MFMA A-fragments, (ACT_C * weight) as bf16 hi/lo ----------------
// slot 0/1: W2 o-tiles; 2/3: W3; 4: W4 (rows 8..15 zero)
// A[m=lane&15][k=(lane>>4)*8 + reg*2 (+1)]; k-even in low16
__global__ void k_wprep(const float* __restrict__ W2, const float* __restrict__ W3,
                        const float* __restrict__ W4,
                        uint32_t* __restrict__ whi, uint32_t* __restrict__ wlo) {
    int e = blockIdx.x * 256 + threadIdx.x;       // 4*5*4*64 = 5120
    if (e >= 5120) return;
    int lane = e & 63;
    int reg  = (e >> 6) & 3;
    int fs   = e >> 8;
    int slot = fs % 5, f = fs / 5;
    int m  = lane & 15;
    int k0 = (lane >> 4) * 8 + reg * 2;
    float wa = 0.f, wb = 0.f;
    if (slot < 2) {
        int o = slot * 16 + m;
        wa = W2[f*1024 + o*32 + k0]; wb = W2[f*1024 + o*32 + k0 + 1];
    } else if (slot < 4) {
        int o = (slot - 2) * 16 + m;
        wa = W3[f*1024 + o*32 + k0]; wb = W3[f*1024 + o*32 + k0 + 1];
    } else if (m < 8) {
        wa = W4[f*256 + m*32 + k0]; wb = W4[f*256 + m*32 + k0 + 1];
    }
    wa *= ACT_C; wb *= ACT_C;                     // fold act scale into weights
    uint32_t ha = bf16_rne(wa), hb = bf16_rne(wb);
    uint32_t la = bf16_rne(wa - __uint_as_float(ha << 16));
    uint32_t lb = bf16_rne(wb - __uint_as_float(hb << 16));
    whi[e] = (ha & 0xffffu) | (hb << 16);
    wlo[e] = (la & 0xffffu) | (lb << 16);
}

// ---------------- MFMA layer: acts as k-pair u32 [16][APAD]; 2-term weight split ----------------
template<int S0>
__device__ __forceinline__ void mlayer(const uint32_t (&Ahi)[5][4], const uint32_t (&Alo)[5][4],
                                       uint32_t* actw, int lane) {
    int g = lane >> 4, nn = lane & 15;
    uint32_t rb[4][4];
    #pragma unroll
    for (int pt = 0; pt < 4; pt++)
        #pragma unroll
        for (int r = 0; r < 4; r++)
            rb[pt][r] = actw[(g * 4 + r) * APAD + pt * 16 + nn];  // all reads before writes
    #pragma unroll
    for (int pt = 0; pt < 4; pt++) {
        FRAG bb;
        #pragma unroll
        for (int r = 0; r < 4; r++) bb.u[r] = rb[pt][r];
        #pragma unroll
        for (int ot = 0; ot < 2; ot++) {
            FRAG ah, al;
            #pragma unroll
            for (int r = 0; r < 4; r++) { ah.u[r] = Ahi[S0+ot][r]; al.u[r] = Alo[S0+ot][r]; }
            f32x4 acc = {0.f, 0.f, 0.f, 0.f};
            acc = __builtin_amdgcn_mfma_f32_16x16x32_bf16(ah.v, bb.v, acc, 0, 0, 0);
            acc = __builtin_amdgcn_mfma_f32_16x16x32_bf16(al.v, bb.v, acc, 0, 0, 0);
            uint32_t p01 = cvt_pk(act_t(acc[0]), act_t(acc[1]));
            uint32_t p23 = cvt_pk(act_t(acc[2]), act_t(acc[3]));
            int cp = ot * 8 + g * 2;
            actw[cp * APAD + pt * 16 + nn]       = p01;
            actw[(cp + 1) * APAD + pt * 16 + nn] = p23;
        }
    }
}

// ---------------- main: one 16.9KB LDS region time-shared as zt -> actb -> red ----------------
__global__ __launch_bounds__(256, 8) void k_main(
    const float* __restrict__ x, const float* __restrict__ ktot,
    const float* __restrict__ biases, const float* __restrict__ W1,
    const uint32_t* __restrict__ whi, const uint32_t* __restrict__ wlo,
    const unsigned* __restrict__ urate, float* __restrict__ out)
{
    int tid = threadIdx.x;
    int lane = tid & 63;
    int f = __builtin_amdgcn_readfirstlane(tid >> 6);

    int blk = blockIdx.x;            // 8192 = b(8) * h(256) * seg(4)
    int seg = blk & 3;
    int h   = (blk >> 2) & 255;
    int b   = blk >> 10;
    int w0  = seg << 6;

    __shared__ uint32_t region[FN * 16 * APAD];   // 16.9 KB: zt | actb | red (time-shared)
    __shared__ float w1l[FN * 32];
    __shared__ float bl[FN];
    float (*zt)[5][68] = reinterpret_cast<float(*)[5][68]>(region);
    float* red = reinterpret_cast<float*>(region);     // red[(o*FN+f)*64+pix], 8KB
    uint32_t* actw = region + f * (16 * APAD);

    if (tid < FN * 32) w1l[tid] = W1[tid] * ACT_C;
    if (tid < FN)      bl[tid]  = biases[tid];

    // ---- phase 1: stage z = floor(x*PV2), rows h-2..h+2, cols w0-2..w0+65 ----
    for (int e = tid; e < CIN * 5 * 68; e += 256) {
        int c  = e / (5 * 68);
        int r  = e % (5 * 68);
        int di = r / 68;
        int dj = r % 68;
        int hh = (h + di + 254) & 255;
        int ww = (w0 + dj + 254) & 255;
        float xv = x[((b * CIN + c) << 16) + (hh << 8) + ww];
        zt[c][di][dj] = floorf(xv * PV2F);
    }
    __syncthreads();

    // ---- phase 2: conv (pixel=lane, filter=f), fp32 exact ----
    const float* kt = ktot + f * 200;
    float accA = 0.f, accB = 0.f;
    #pragma unroll
    for (int c = 0; c < CIN; c++) {
        #pragma unroll
        for (int di = 0; di < 5; di++) {
            #pragma unroll
            for (int dj = 0; dj < 5; dj++) {
                float v = zt[c][di][lane + dj] * kt[c * 25 + di * 5 + dj];
                if ((di ^ c) & 1) accA += v; else accB += v;
            }
        }
    }
    float p  = floorf(accA + accB + bl[f]) / PV2F;
    float t0 = floorf(p * PV1F);
    __syncthreads();                 // zt dead -> region becomes actb

    // ---- load A-fragments ----
    uint32_t Ahi[5][4], Alo[5][4];
    #pragma unroll
    for (int s5 = 0; s5 < 5; s5++)
        #pragma unroll
        for (int r = 0; r < 4; r++) {
            int idx = ((f * 5 + s5) * 4 + r) * 64 + lane;
            Ahi[s5][r] = whi[idx];
            Alo[s5][r] = wlo[idx];
        }

    // ---- phase 3: layer 1 (rank-1), acts packed as k-pairs; wave-private slice ----
    #pragma unroll
    for (int op = 0; op < 16; op++) {
        float a0 = act_t(w1l[f * 32 + 2*op]     * t0);
        float a1 = act_t(w1l[f * 32 + 2*op + 1] * t0);
        actw[op * APAD + lane] = cvt_pk(a0, a1);
    }

    // ---- layers 2,3 via MFMA (wave-private actb slice, no barriers) ----
    mlayer<0>(Ahi, Alo, actw, lane);
    mlayer<2>(Ahi, Alo, actw, lane);

    // ---- phase 4: layer 4 rb loads, then barrier, then red writes (red aliases actb) ----
    int g = lane >> 4, nn = lane & 15;
    uint32_t rb[4][4];
    #pragma unroll
    for (int pt = 0; pt < 4; pt++)
        #pragma unroll
        for (int r = 0; r < 4; r++)
            rb[pt][r] = actw[(g * 4 + r) * APAD + pt * 16 + nn];
    __syncthreads();                 // all waves done reading actb -> region becomes red

    #pragma unroll
    for (int pt = 0; pt < 4; pt++) {
        FRAG bb, ah, al;
        #pragma unroll
        for (int r = 0; r < 4; r++) {
            bb.u[r] = rb[pt][r];
            ah.u[r] = Ahi[4][r]; al.u[r] = Alo[4][r];
        }
        f32x4 acc = {0.f, 0.f, 0.f, 0.f};
        acc = __builtin_amdgcn_mfma_f32_16x16x32_bf16(ah.v, bb.v, acc, 0, 0, 0);
        acc = __builtin_amdgcn_mfma_f32_16x16x32_bf16(al.v, bb.v, acc, 0, 0, 0);
        if (lane < 32) {
            #pragma unroll
            for (int r = 0; r < 4; r++) {
                int o = g * 4 + r;                // 0..7
                red[(o * FN + f) * 64 + pt * 16 + nn] = act_out(acc[r]);
            }
        }
    }
    __syncthreads();

    // ---- phase 5: second-smallest across f + residual + clip ----
    unsigned ub = urate[0];
    float ur = (ub < 0x38000000u) ? (float)(int)ub : __uint_as_float(ub);

    #pragma unroll
    for (int q = 0; q < 2; q++) {
        int pidx = tid + q * 256;
        int o   = pidx >> 6;
        int pix = pidx & 63;
        float v0 = red[(o * FN + 0) * 64 + pix], v1 = red[(o * FN + 1) * 64 + pix];
        float v2 = red[(o * FN + 2) * 64 + pix], v3 = red[(o * FN + 3) * 64 + pix];
        float lo01 = fminf(v0, v1), hi01 = fmaxf(v0, v1);
        float lo23 = fminf(v2, v3), hi23 = fmaxf(v2, v3);
        float second = fminf(fmaxf(lo01, lo23), fminf(hi01, hi23));
        int oidx = ((b * CIN + o) << 16) + (h << 8) + (w0 + pix);
        float xv = x[oidx];
        out[oidx] = fminf(fmaxf(xv + second * ur, 0.0f), 1.0f);
    }
}

extern "C" void kernel_launch(void* const* d_in, const int* in_sizes, int n_in,
                              void* d_out, int out_size, void* d_ws, size_t ws_size,
                              hipStream_t stream) {
    const float* x       = (const float*)d_in[0];
    const float* kernels = (const float*)d_in[1];
    const float* biases  = (const float*)d_in[2];
    const float* W1      = (const float*)d_in[3];
    const float* W2      = (const float*)d_in[4];
    const float* W3      = (const float*)d_in[5];
    const float* W4      = (const float*)d_in[6];
    const unsigned* ur   = (const unsigned*)d_in[7];
    float* out = (float*)d_out;

    float*    ktot = (float*)d_ws;                      // 800 floats
    uint32_t* whi  = (uint32_t*)((float*)d_ws + 800);   // 5120 u32
    uint32_t* wlo  = whi + 5120;                        // 5120 u32

    k_prep<<<32, 64, 0, stream>>>(kernels, ktot);
    k_wprep<<<20, 256, 0, stream>>>(W2, W3, W4, whi, wlo);
    k_main<<<8 * 256 * 4, 256, 0, stream>>>(x, ktot, biases, W1, whi, wlo, ur, out);
}